// Round 9
// baseline (228.219 us; speedup 1.0000x reference)
//
#include <hip/hip_runtime.h>
#include <hip/hip_bf16.h>

// ---------------------------------------------------------------------------
// CapsNet forward, fp32. B=512.
// convs: BANDED blocks (grid = B x HOUT/BANDH), guarded padded staging in LDS,
//        fused relu+pool, one task per thread.
// routing1 SPLIT (unchanged from round 8):
//   K1 routing1_einsum: lane==r, wave==n, G=8 b/block; u_hat -> ws.
//   K2 routing1_iter: thread=(n, r-octet), register-resident iterations.
// routing2+fc: register-resident, 32-lane butterflies (unchanged).
// ---------------------------------------------------------------------------

// Banded fused conv3x3(SAME) + ReLU + maxpool2. Grid = (B, HOUT/BANDH).
template<int CIN, int COUT, int HIN, int NO, int BANDH>
__global__ __launch_bounds__(256)
void conv_relu_pool(const float* __restrict__ in, const float* __restrict__ w,
                    const float* __restrict__ bias, float* __restrict__ out)
{
    constexpr int HOUT = HIN / 2;
    constexpr int ROWS = 2 * BANDH + 2;
    constexpr int PC = (HIN + 2 + 3) & ~3;
    constexpr int NS = HIN / 8;
    constexpr int XWORDS = CIN * ROWS * PC;
    constexpr int WWORDS = CIN * 9 * COUT;
    static_assert((COUT / NO) * BANDH * NS == 256, "one task per thread");

    __shared__ float xin[CIN][ROWS][PC];
    __shared__ float wt[WWORDS];                // [c][k][o]
    __shared__ float bl[COUT];

    const int tid  = threadIdx.x;
    const int b    = blockIdx.x;
    const int band = blockIdx.y;
    const int y0   = 2 * (band * BANDH) - 1;    // global y of LDS row 0

    for (int i = tid; i < XWORDS; i += 256) ((float*)xin)[i] = 0.f;
    for (int i = tid; i < WWORDS; i += 256) {
        int o = i % COUT, k = (i / COUT) % 9, c = i / (COUT * 9);
        wt[i] = w[(o * CIN + c) * 9 + k];
    }
    if (tid < COUT) bl[tid] = bias[tid];
    __syncthreads();

    const float4* gin = (const float4*)(in + (size_t)b * CIN * HIN * HIN);
    constexpr int CHUNKS = CIN * ROWS * (HIN / 4);
    for (int i = tid; i < CHUNKS; i += 256) {
        int ch = i % (HIN / 4);
        int ly = (i / (HIN / 4)) % ROWS;
        int c  = i / ((HIN / 4) * ROWS);
        int y  = y0 + ly;
        if (y >= 0 && y < HIN) {
            float4 v = gin[(c * HIN + y) * (HIN / 4) + ch];
            float* dst = &xin[c][ly][1 + ch * 4];
            dst[0] = v.x; dst[1] = v.y; dst[2] = v.z; dst[3] = v.w;
        }
    }
    __syncthreads();

    const int s  = tid % NS;
    const int py = (tid / NS) % BANDH;
    const int o0 = (tid / (NS * BANDH)) * NO;
    const int X0 = s * 8;

    float acc[NO][2][8];
#pragma unroll
    for (int n = 0; n < NO; ++n)
#pragma unroll
        for (int q = 0; q < 2; ++q)
#pragma unroll
            for (int j = 0; j < 8; ++j) acc[n][q][j] = 0.f;

    for (int c = 0; c < CIN; ++c) {
        float rows[4][12];
#pragma unroll
        for (int rr = 0; rr < 4; ++rr) {
            const float4* src = (const float4*)&xin[c][2 * py + rr][X0];
#pragma unroll
            for (int j = 0; j < 3; ++j) {
                float4 v = src[j];
                rows[rr][j * 4 + 0] = v.x; rows[rr][j * 4 + 1] = v.y;
                rows[rr][j * 4 + 2] = v.z; rows[rr][j * 4 + 3] = v.w;
            }
        }
        const float* wc = wt + c * 9 * COUT;
#pragma unroll
        for (int ky = 0; ky < 3; ++ky) {
#pragma unroll
            for (int n = 0; n < NO; ++n) {
                const float w0 = wc[(ky * 3 + 0) * COUT + o0 + n];
                const float w1 = wc[(ky * 3 + 1) * COUT + o0 + n];
                const float w2 = wc[(ky * 3 + 2) * COUT + o0 + n];
#pragma unroll
                for (int j = 0; j < 8; ++j) {
                    acc[n][0][j] = fmaf(rows[ky][j],     w0, acc[n][0][j]);
                    acc[n][0][j] = fmaf(rows[ky][j + 1], w1, acc[n][0][j]);
                    acc[n][0][j] = fmaf(rows[ky][j + 2], w2, acc[n][0][j]);
                    acc[n][1][j] = fmaf(rows[ky + 1][j],     w0, acc[n][1][j]);
                    acc[n][1][j] = fmaf(rows[ky + 1][j + 1], w1, acc[n][1][j]);
                    acc[n][1][j] = fmaf(rows[ky + 1][j + 2], w2, acc[n][1][j]);
                }
            }
        }
    }
#pragma unroll
    for (int n = 0; n < NO; ++n) {
        const float bv = bl[o0 + n];
        float4 ov;
        float* p = (float*)&ov;
#pragma unroll
        for (int j = 0; j < 4; ++j) {
            float m = fmaxf(fmaxf(acc[n][0][2 * j], acc[n][0][2 * j + 1]),
                            fmaxf(acc[n][1][2 * j], acc[n][1][2 * j + 1]));
            p[j] = fmaxf(m + bv, 0.f);
        }
        float* po = out + (((size_t)b * COUT + o0 + n) * HOUT + band * BANDH + py) * HOUT + s * 4;
        *(float4*)po = ov;
    }
}

// W[n][r][c][o] -> Wt[n][c][r][o]  (n=32, r=64, c=32, o=8), float4 granules.
__global__ __launch_bounds__(256)
void transpose_w1(const float* __restrict__ W, float* __restrict__ Wt)
{
    int idx = blockIdx.x * 256 + threadIdx.x;
    if (idx >= 32 * 32 * 64 * 2) return;
    int half = idx & 1;
    int r    = (idx >> 1) & 63;
    int c    = (idx >> 7) & 31;
    int n    = idx >> 12;
    ((float4*)Wt)[idx] =
        ((const float4*)W)[(((n * 64 + r) * 32 + c) << 1) + half];
}

// K1: u_hat einsum. lane==r, wave==n (quad), G=8 batch elems per block.
__global__ __launch_bounds__(256)
void routing1_einsum(const float* __restrict__ h3, const float* __restrict__ Wt,
                     float* __restrict__ uhat)
{
    constexpr int C = 32, R = 64, O = 8, G = 8;
    const int lane = threadIdx.x & 63;
    const int n    = blockIdx.y * 4 + (threadIdx.x >> 6);
    const int b0   = blockIdx.x * G;

    float u[G][O];
#pragma unroll
    for (int g = 0; g < G; ++g)
#pragma unroll
        for (int o = 0; o < O; ++o) u[g][o] = 0.f;

    const float4* wp = (const float4*)Wt + (size_t)n * C * R * 2;
    const float* xb = h3 + (size_t)b0 * (C * R) + lane;

#pragma unroll 4
    for (int c = 0; c < C; ++c) {
        float xv[G];
#pragma unroll
        for (int g = 0; g < G; ++g) xv[g] = xb[(size_t)g * (C * R) + c * R];
        float4 w0 = wp[(c * R + lane) * 2];
        float4 w1 = wp[(c * R + lane) * 2 + 1];
#pragma unroll
        for (int g = 0; g < G; ++g) {
            u[g][0] = fmaf(xv[g], w0.x, u[g][0]);
            u[g][1] = fmaf(xv[g], w0.y, u[g][1]);
            u[g][2] = fmaf(xv[g], w0.z, u[g][2]);
            u[g][3] = fmaf(xv[g], w0.w, u[g][3]);
            u[g][4] = fmaf(xv[g], w1.x, u[g][4]);
            u[g][5] = fmaf(xv[g], w1.y, u[g][5]);
            u[g][6] = fmaf(xv[g], w1.z, u[g][6]);
            u[g][7] = fmaf(xv[g], w1.w, u[g][7]);
        }
    }
#pragma unroll
    for (int g = 0; g < G; ++g) {
        float4* dst = (float4*)(uhat + (((size_t)(b0 + g) * 32 + n) * R + lane) * O);
        dst[0] = make_float4(u[g][0], u[g][1], u[g][2], u[g][3]);
        dst[1] = make_float4(u[g][4], u[g][5], u[g][6], u[g][7]);
    }
}

// K2: routing iterations. One block per b; thread = (n, rp).
__global__ __launch_bounds__(256)
void routing1_iter(const float* __restrict__ uhat, float* __restrict__ v1)
{
    constexpr int O = 8;
    const int t  = threadIdx.x;
    const int b  = blockIdx.x;
    const int n  = t >> 3;
    const int rp = t & 7;

    float u[8][O];
    {
        const float4* up = (const float4*)(uhat + (((size_t)b * 32 + n) * 64 + rp * 8) * O);
#pragma unroll
        for (int i = 0; i < 16; ++i) {
            float4 w = up[i];
            u[i >> 1][(i & 1) * 4 + 0] = w.x;
            u[i >> 1][(i & 1) * 4 + 1] = w.y;
            u[i >> 1][(i & 1) * 4 + 2] = w.z;
            u[i >> 1][(i & 1) * 4 + 3] = w.w;
        }
    }

    float bij[8];
#pragma unroll
    for (int k = 0; k < 8; ++k) bij[k] = 0.f;
    float s[O];

#pragma unroll
    for (int it = 0; it < 3; ++it) {
        float e[8];
        float inv;
        if (it == 0) {
#pragma unroll
            for (int k = 0; k < 8; ++k) e[k] = 1.f;
            inv = 1.0f / 64.0f;
        } else {
            float mx = bij[0];
#pragma unroll
            for (int k = 1; k < 8; ++k) mx = fmaxf(mx, bij[k]);
#pragma unroll
            for (int m = 1; m < 8; m <<= 1) mx = fmaxf(mx, __shfl_xor(mx, m, 64));
            float sum = 0.f;
#pragma unroll
            for (int k = 0; k < 8; ++k) { e[k] = __expf(bij[k] - mx); sum += e[k]; }
#pragma unroll
            for (int m = 1; m < 8; m <<= 1) sum += __shfl_xor(sum, m, 64);
            inv = 1.f / sum;
        }
        float ta[O];
#pragma unroll
        for (int o = 0; o < O; ++o) ta[o] = 0.f;
#pragma unroll
        for (int k = 0; k < 8; ++k)
#pragma unroll
            for (int o = 0; o < O; ++o) ta[o] = fmaf(e[k], u[k][o], ta[o]);
#pragma unroll
        for (int m = 1; m < 8; m <<= 1)
#pragma unroll
            for (int o = 0; o < O; ++o) ta[o] += __shfl_xor(ta[o], m, 64);
        float nr = 0.f;
#pragma unroll
        for (int o = 0; o < O; ++o) { s[o] = ta[o] * inv; nr = fmaf(s[o], s[o], nr); }
        float scale = nr / (1.f + nr) / sqrtf(nr + 1e-9f);
#pragma unroll
        for (int o = 0; o < O; ++o) s[o] *= scale;
        if (it < 2) {
#pragma unroll
            for (int k = 0; k < 8; ++k) {
                float d = 0.f;
#pragma unroll
                for (int o = 0; o < O; ++o) d = fmaf(u[k][o], s[o], d);
                bij[k] += d;
            }
        }
    }
    float outv = s[0];
#pragma unroll
    for (int o = 1; o < O; ++o) outv = (rp == o) ? s[o] : outv;
    v1[(size_t)b * 256 + n * 8 + rp] = outv;
}

// Routing stage 2 + FC, register-resident. One block per b, 4 waves.
__global__ __launch_bounds__(256)
void routing2_fc(const float* __restrict__ v1, const float* __restrict__ W,
                 const float* __restrict__ fcw, const float* __restrict__ fcb,
                 float* __restrict__ out)
{
    constexpr int R = 32, C = 8, O = 16;
    __shared__ float vv[240];

    const int t  = threadIdx.x;
    const int b  = blockIdx.x;
    const int wv = t >> 6;
    const int lane = t & 63;
    const int nh = lane >> 5;
    const int r  = lane & 31;

    const float4* xr = (const float4*)(v1 + (size_t)b * 256 + r * 8);
    float4 x0 = xr[0], x1 = xr[1];
    float xv[8] = {x0.x, x0.y, x0.z, x0.w, x1.x, x1.y, x1.z, x1.w};

    float u[2][O];
    int nn[2];
#pragma unroll
    for (int p = 0; p < 2; ++p) {
        int n = wv * 4 + p * 2 + nh;
        nn[p] = n;
        int ncl = n < 15 ? n : 14;
        const float4* wp = (const float4*)(W + ((size_t)(ncl * R + r) * C) * O);
#pragma unroll
        for (int o = 0; o < O; ++o) u[p][o] = 0.f;
#pragma unroll
        for (int c = 0; c < C; ++c) {
#pragma unroll
            for (int j = 0; j < 4; ++j) {
                float4 w4 = wp[c * 4 + j];
                u[p][j * 4 + 0] = fmaf(xv[c], w4.x, u[p][j * 4 + 0]);
                u[p][j * 4 + 1] = fmaf(xv[c], w4.y, u[p][j * 4 + 1]);
                u[p][j * 4 + 2] = fmaf(xv[c], w4.z, u[p][j * 4 + 2]);
                u[p][j * 4 + 3] = fmaf(xv[c], w4.w, u[p][j * 4 + 3]);
            }
        }
    }

    float bij[2] = {0.f, 0.f};
    float s[2][O];
#pragma unroll
    for (int it = 0; it < 3; ++it) {
#pragma unroll
        for (int p = 0; p < 2; ++p) {
            float cc;
            if (it == 0) {
                cc = 1.0f / 32.0f;
            } else {
                float mx = bij[p];
#pragma unroll
                for (int w = 1; w < 32; w <<= 1) mx = fmaxf(mx, __shfl_xor(mx, w, 32));
                float e = __expf(bij[p] - mx);
                float sum = e;
#pragma unroll
                for (int w = 1; w < 32; w <<= 1) sum += __shfl_xor(sum, w, 32);
                cc = e / sum;
            }
#pragma unroll
            for (int o = 0; o < O; ++o) s[p][o] = cc * u[p][o];
        }
#pragma unroll
        for (int w = 1; w < 32; w <<= 1)
#pragma unroll
            for (int p = 0; p < 2; ++p)
#pragma unroll
                for (int o = 0; o < O; ++o) s[p][o] += __shfl_xor(s[p][o], w, 32);
#pragma unroll
        for (int p = 0; p < 2; ++p) {
            float nr = 0.f;
#pragma unroll
            for (int o = 0; o < O; ++o) nr = fmaf(s[p][o], s[p][o], nr);
            float scale = nr / (1.f + nr) / sqrtf(nr + 1e-9f);
#pragma unroll
            for (int o = 0; o < O; ++o) s[p][o] *= scale;
            if (it < 2) {
                float d = 0.f;
#pragma unroll
                for (int o = 0; o < O; ++o) d = fmaf(u[p][o], s[p][o], d);
                bij[p] += d;
            }
        }
    }
#pragma unroll
    for (int p = 0; p < 2; ++p) {
        float outv = 0.f;
#pragma unroll
        for (int o = 0; o < O; ++o) outv = (r == o) ? s[p][o] : outv;
        if (r < O && nn[p] < 15) vv[nn[p] * O + r] = outv;
    }
    __syncthreads();
    if (t < 240) {
        int j = t >> 4, k0 = t & 15;
        float acc = 0.f;
        for (int k = k0; k < 240; k += 16) acc = fmaf(vv[k], fcw[j * 240 + k], acc);
#pragma unroll
        for (int w = 1; w < 16; w <<= 1) acc += __shfl_xor(acc, w, 16);
        if (k0 == 0) out[(size_t)b * 15 + j] = acc + fcb[j];
    }
}

extern "C" void kernel_launch(void* const* d_in, const int* in_sizes, int n_in,
                              void* d_out, int out_size, void* d_ws, size_t ws_size,
                              hipStream_t stream) {
    const float* x    = (const float*)d_in[0];
    const float* w1   = (const float*)d_in[1];
    const float* b1   = (const float*)d_in[2];
    const float* w2   = (const float*)d_in[3];
    const float* b2   = (const float*)d_in[4];
    const float* w3   = (const float*)d_in[5];
    const float* b3   = (const float*)d_in[6];
    const float* rw1  = (const float*)d_in[7];
    const float* rw2  = (const float*)d_in[8];
    const float* fcw  = (const float*)d_in[9];
    const float* fcb  = (const float*)d_in[10];
    float* out = (float*)d_out;

    const int B = 512;
    float* ws = (float*)d_ws;
    // Memory map (floats). uhat overlays h1+h2 (dead after conv3).
    float* uhat = ws;                                // [512,32,64,8] = 8,388,608
    float* h1   = ws;                                // [512,8,32,32] = 4,194,304
    float* h2   = h1 + (size_t)B * 8 * 32 * 32;      // [512,16,16,16]= 2,097,152
    float* h3   = uhat + (size_t)8388608;            // [512,32,8,8]  = 1,048,576
    float* v1   = h3 + (size_t)B * 32 * 8 * 8;       // [512,32,8]    =   131,072
    float* Wt   = v1 + (size_t)B * 256;              // [32,32,64,8]  =   524,288

    conv_relu_pool<3, 8, 64, 4, 16><<<dim3(B, 2), 256, 0, stream>>>(x, w1, b1, h1);
    conv_relu_pool<8, 16, 32, 2, 8><<<dim3(B, 2), 256, 0, stream>>>(h1, w2, b2, h2);
    conv_relu_pool<16, 32, 16, 2, 8><<<dim3(B, 1), 256, 0, stream>>>(h2, w3, b3, h3);
    transpose_w1<<<(32 * 32 * 64 * 2 + 255) / 256, 256, 0, stream>>>(rw1, Wt);
    {
        dim3 grid(B / 8, 8);   // K1: 512 blocks
        routing1_einsum<<<grid, 256, 0, stream>>>(h3, Wt, uhat);
    }
    routing1_iter<<<B, 256, 0, stream>>>(uhat, v1);
    routing2_fc<<<B, 256, 0, stream>>>(v1, rw2, fcw, fcb, out);
}

// Round 10
// 199.122 us; speedup vs baseline: 1.1461x; 1.1461x over previous
//
#include <hip/hip_runtime.h>
#include <hip/hip_bf16.h>

// ---------------------------------------------------------------------------
// CapsNet forward, fp32. B=512.
// conv_stack: ALL THREE convs fused, one block per image, LDS-resident
//   intermediates (region-reused, 72.6KB -> 2 blocks/CU). Writes only h3.
// routing1 SPLIT (unchanged from round 8):
//   K1 routing1_einsum: lane==r, wave==n, G=8 b/block; u_hat -> ws.
//   K2 routing1_iter: thread=(n, r-octet), register-resident iterations.
// routing2+fc: register-resident, 32-lane butterflies (unchanged).
// ---------------------------------------------------------------------------

// LDS word map (18152 words = 72.6 KB):
//  A  @0     (6936): conv1 xbuf [3][34][68]  -> reused as o2 [16][18][20]
//  B  @6936  (9792): o1 [8][34][36]          -> reused as w3(4608)+o3(2048)
//  w1 @16728 (216), w2 @16944 (1152), biases @18096 (56)
__global__ __launch_bounds__(256)
void conv_stack(const float* __restrict__ x,
                const float* __restrict__ w1g, const float* __restrict__ b1g,
                const float* __restrict__ w2g, const float* __restrict__ b2g,
                const float* __restrict__ w3g, const float* __restrict__ b3g,
                float* __restrict__ h3)
{
    __shared__ float lds[18152];
    float* A  = lds;            // [3][34][68] then [16][18][20]
    float* o1 = lds + 6936;     // [8][34][36]
    float* w3 = lds + 6936;     // [16][9][32] (after o1 dead)
    float* o3 = lds + 11544;    // [32][64]
    float* w1 = lds + 16728;    // [3][9][8]
    float* w2 = lds + 16944;    // [8][9][16]
    float* bb = lds + 18096;    // b1[0..8) b2[8..24) b3[24..56)

    const int tid = threadIdx.x;
    const int b   = blockIdx.x;

    // ---- init: zero A+B (4182 float4), stage w1/w2/biases ----
    {
        float4 z = make_float4(0.f, 0.f, 0.f, 0.f);
        for (int i = tid; i < 4182; i += 256) ((float4*)lds)[i] = z;
        for (int i = tid; i < 216; i += 256) {
            int o = i % 8, k = (i / 8) % 9, c = i / 72;
            w1[i] = w1g[(o * 3 + c) * 9 + k];
        }
        for (int i = tid; i < 1152; i += 256) {
            int o = i % 16, k = (i / 16) % 9, c = i / 144;
            w2[i] = w2g[(o * 8 + c) * 9 + k];
        }
        if (tid < 8)  bb[tid]      = b1g[tid];
        if (tid < 16) bb[8 + tid]  = b2g[tid];
        if (tid < 32) bb[24 + tid] = b3g[tid];
    }
    const float4* gin = (const float4*)(x + (size_t)b * 3 * 64 * 64);

    // stage conv1 band 0 (y0 = -1): write-always (zeros when OOB)
    auto stage_band = [&](int y0) {
        for (int i = tid; i < 3 * 34 * 16; i += 256) {
            int ch = i % 16;
            int ly = (i / 16) % 34;
            int c  = i / (16 * 34);
            int y  = y0 + ly;
            float4 v = make_float4(0.f, 0.f, 0.f, 0.f);
            if (y >= 0 && y < 64) v = gin[(c * 64 + y) * 16 + ch];
            float* d = &A[(c * 34 + ly) * 68 + 1 + ch * 4];
            d[0] = v.x; d[1] = v.y; d[2] = v.z; d[3] = v.w;
        }
    };
    stage_band(-1);
    __syncthreads();

    // ---- conv1 (two bands of 16 pooled rows), NO=4 ----
    auto conv1_band = [&](int band) {
        const int s  = tid & 7;            // 8 strips of 8 input cols
        const int py = (tid >> 3) & 15;    // band-local pooled row
        const int og = tid >> 7;           // 0..1 -> chans og*4..+3
        const int X0 = 8 * s;
        float acc[4][2][8];
#pragma unroll
        for (int n = 0; n < 4; ++n)
#pragma unroll
            for (int q = 0; q < 2; ++q)
#pragma unroll
                for (int j = 0; j < 8; ++j) acc[n][q][j] = 0.f;
#pragma unroll
        for (int c = 0; c < 3; ++c) {
            float rows[4][12];
#pragma unroll
            for (int rr = 0; rr < 4; ++rr) {
                const float4* src = (const float4*)&A[(c * 34 + 2 * py + rr) * 68 + X0];
#pragma unroll
                for (int j = 0; j < 3; ++j) {
                    float4 v = src[j];
                    rows[rr][j * 4 + 0] = v.x; rows[rr][j * 4 + 1] = v.y;
                    rows[rr][j * 4 + 2] = v.z; rows[rr][j * 4 + 3] = v.w;
                }
            }
            const float* wc = w1 + c * 72;
#pragma unroll
            for (int ky = 0; ky < 3; ++ky)
#pragma unroll
                for (int n = 0; n < 4; ++n) {
                    const float q0 = wc[(ky * 3 + 0) * 8 + og * 4 + n];
                    const float q1 = wc[(ky * 3 + 1) * 8 + og * 4 + n];
                    const float q2 = wc[(ky * 3 + 2) * 8 + og * 4 + n];
#pragma unroll
                    for (int j = 0; j < 8; ++j) {
                        acc[n][0][j] = fmaf(rows[ky][j],     q0, acc[n][0][j]);
                        acc[n][0][j] = fmaf(rows[ky][j + 1], q1, acc[n][0][j]);
                        acc[n][0][j] = fmaf(rows[ky][j + 2], q2, acc[n][0][j]);
                        acc[n][1][j] = fmaf(rows[ky + 1][j],     q0, acc[n][1][j]);
                        acc[n][1][j] = fmaf(rows[ky + 1][j + 1], q1, acc[n][1][j]);
                        acc[n][1][j] = fmaf(rows[ky + 1][j + 2], q2, acc[n][1][j]);
                    }
                }
        }
#pragma unroll
        for (int n = 0; n < 4; ++n) {
            const float bv = bb[og * 4 + n];
            const int row = 1 + band * 16 + py;
#pragma unroll
            for (int j = 0; j < 4; ++j) {
                float m = fmaxf(fmaxf(acc[n][0][2 * j], acc[n][0][2 * j + 1]),
                                fmaxf(acc[n][1][2 * j], acc[n][1][2 * j + 1]));
                o1[((og * 4 + n) * 34 + row) * 36 + 1 + 4 * s + j] = fmaxf(m + bv, 0.f);
            }
        }
    };
    conv1_band(0);
    __syncthreads();
    stage_band(31);
    __syncthreads();
    conv1_band(1);
    __syncthreads();

    // ---- re-zero A (o2 buffer needs zero halo) ----
    {
        float4 z = make_float4(0.f, 0.f, 0.f, 0.f);
        for (int i = tid; i < 1734; i += 256) ((float4*)A)[i] = z;
    }
    __syncthreads();

    // ---- conv2: o1 [8][34][36] -> o2(A) [16][18][20], NO=4 ----
    {
        const int s  = tid & 3;            // 4 strips of 8 input cols
        const int py = (tid >> 2) & 15;
        const int og = tid >> 6;           // 0..3 -> chans og*4..+3
        const int X0 = 8 * s;
        float acc[4][2][8];
#pragma unroll
        for (int n = 0; n < 4; ++n)
#pragma unroll
            for (int q = 0; q < 2; ++q)
#pragma unroll
                for (int j = 0; j < 8; ++j) acc[n][q][j] = 0.f;
        for (int c = 0; c < 8; ++c) {
            float rows[4][12];
#pragma unroll
            for (int rr = 0; rr < 4; ++rr) {
                const float4* src = (const float4*)&o1[(c * 34 + 2 * py + rr) * 36 + X0];
#pragma unroll
                for (int j = 0; j < 3; ++j) {
                    float4 v = src[j];
                    rows[rr][j * 4 + 0] = v.x; rows[rr][j * 4 + 1] = v.y;
                    rows[rr][j * 4 + 2] = v.z; rows[rr][j * 4 + 3] = v.w;
                }
            }
            const float* wc = w2 + c * 144;
#pragma unroll
            for (int ky = 0; ky < 3; ++ky)
#pragma unroll
                for (int n = 0; n < 4; ++n) {
                    const float q0 = wc[(ky * 3 + 0) * 16 + og * 4 + n];
                    const float q1 = wc[(ky * 3 + 1) * 16 + og * 4 + n];
                    const float q2 = wc[(ky * 3 + 2) * 16 + og * 4 + n];
#pragma unroll
                    for (int j = 0; j < 8; ++j) {
                        acc[n][0][j] = fmaf(rows[ky][j],     q0, acc[n][0][j]);
                        acc[n][0][j] = fmaf(rows[ky][j + 1], q1, acc[n][0][j]);
                        acc[n][0][j] = fmaf(rows[ky][j + 2], q2, acc[n][0][j]);
                        acc[n][1][j] = fmaf(rows[ky + 1][j],     q0, acc[n][1][j]);
                        acc[n][1][j] = fmaf(rows[ky + 1][j + 1], q1, acc[n][1][j]);
                        acc[n][1][j] = fmaf(rows[ky + 1][j + 2], q2, acc[n][1][j]);
                    }
                }
        }
#pragma unroll
        for (int n = 0; n < 4; ++n) {
            const float bv = bb[8 + og * 4 + n];
#pragma unroll
            for (int j = 0; j < 4; ++j) {
                float m = fmaxf(fmaxf(acc[n][0][2 * j], acc[n][0][2 * j + 1]),
                                fmaxf(acc[n][1][2 * j], acc[n][1][2 * j + 1]));
                A[((og * 4 + n) * 18 + 1 + py) * 20 + 1 + 4 * s + j] = fmaxf(m + bv, 0.f);
            }
        }
    }
    __syncthreads();

    // ---- stage w3 into B (o1 dead) ----
    for (int i = tid; i < 4608; i += 256) {
        int o = i % 32, k = (i / 32) % 9, c = i / 288;
        w3[i] = w3g[(o * 16 + c) * 9 + k];
    }
    __syncthreads();

    // ---- conv3: o2(A) [16][18][20] -> o3 [32][64], NO=2 ----
    {
        const int s  = tid & 1;            // 2 strips of 8 input cols
        const int py = (tid >> 1) & 7;
        const int og = tid >> 4;           // 0..15 -> chans og*2..+1
        const int X0 = 8 * s;
        float acc[2][2][8];
#pragma unroll
        for (int n = 0; n < 2; ++n)
#pragma unroll
            for (int q = 0; q < 2; ++q)
#pragma unroll
                for (int j = 0; j < 8; ++j) acc[n][q][j] = 0.f;
        for (int c = 0; c < 16; ++c) {
            float rows[4][12];
#pragma unroll
            for (int rr = 0; rr < 4; ++rr) {
                const float4* src = (const float4*)&A[(c * 18 + 2 * py + rr) * 20 + X0];
#pragma unroll
                for (int j = 0; j < 3; ++j) {
                    float4 v = src[j];
                    rows[rr][j * 4 + 0] = v.x; rows[rr][j * 4 + 1] = v.y;
                    rows[rr][j * 4 + 2] = v.z; rows[rr][j * 4 + 3] = v.w;
                }
            }
            const float* wc = w3 + c * 288;
#pragma unroll
            for (int ky = 0; ky < 3; ++ky)
#pragma unroll
                for (int n = 0; n < 2; ++n) {
                    const float q0 = wc[(ky * 3 + 0) * 32 + og * 2 + n];
                    const float q1 = wc[(ky * 3 + 1) * 32 + og * 2 + n];
                    const float q2 = wc[(ky * 3 + 2) * 32 + og * 2 + n];
#pragma unroll
                    for (int j = 0; j < 8; ++j) {
                        acc[n][0][j] = fmaf(rows[ky][j],     q0, acc[n][0][j]);
                        acc[n][0][j] = fmaf(rows[ky][j + 1], q1, acc[n][0][j]);
                        acc[n][0][j] = fmaf(rows[ky][j + 2], q2, acc[n][0][j]);
                        acc[n][1][j] = fmaf(rows[ky + 1][j],     q0, acc[n][1][j]);
                        acc[n][1][j] = fmaf(rows[ky + 1][j + 1], q1, acc[n][1][j]);
                        acc[n][1][j] = fmaf(rows[ky + 1][j + 2], q2, acc[n][1][j]);
                    }
                }
        }
#pragma unroll
        for (int n = 0; n < 2; ++n) {
            const float bv = bb[24 + og * 2 + n];
            float4 ov;
            float* p = (float*)&ov;
#pragma unroll
            for (int j = 0; j < 4; ++j) {
                float m = fmaxf(fmaxf(acc[n][0][2 * j], acc[n][0][2 * j + 1]),
                                fmaxf(acc[n][1][2 * j], acc[n][1][2 * j + 1]));
                p[j] = fmaxf(m + bv, 0.f);
            }
            *(float4*)&o3[(og * 2 + n) * 64 + py * 8 + 4 * s] = ov;
        }
    }
    __syncthreads();

    // ---- write h3 (coalesced) ----
    {
        float4* dst = (float4*)(h3 + (size_t)b * 2048);
        const float4* src = (const float4*)o3;
        for (int i = tid; i < 512; i += 256) dst[i] = src[i];
    }
}

// W[n][r][c][o] -> Wt[n][c][r][o]  (n=32, r=64, c=32, o=8), float4 granules.
__global__ __launch_bounds__(256)
void transpose_w1(const float* __restrict__ W, float* __restrict__ Wt)
{
    int idx = blockIdx.x * 256 + threadIdx.x;
    if (idx >= 32 * 32 * 64 * 2) return;
    int half = idx & 1;
    int r    = (idx >> 1) & 63;
    int c    = (idx >> 7) & 31;
    int n    = idx >> 12;
    ((float4*)Wt)[idx] =
        ((const float4*)W)[(((n * 64 + r) * 32 + c) << 1) + half];
}

// K1: u_hat einsum. lane==r, wave==n (quad), G=8 batch elems per block.
__global__ __launch_bounds__(256)
void routing1_einsum(const float* __restrict__ h3, const float* __restrict__ Wt,
                     float* __restrict__ uhat)
{
    constexpr int C = 32, R = 64, O = 8, G = 8;
    const int lane = threadIdx.x & 63;
    const int n    = blockIdx.y * 4 + (threadIdx.x >> 6);
    const int b0   = blockIdx.x * G;

    float u[G][O];
#pragma unroll
    for (int g = 0; g < G; ++g)
#pragma unroll
        for (int o = 0; o < O; ++o) u[g][o] = 0.f;

    const float4* wp = (const float4*)Wt + (size_t)n * C * R * 2;
    const float* xb = h3 + (size_t)b0 * (C * R) + lane;

#pragma unroll 4
    for (int c = 0; c < C; ++c) {
        float xv[G];
#pragma unroll
        for (int g = 0; g < G; ++g) xv[g] = xb[(size_t)g * (C * R) + c * R];
        float4 w0 = wp[(c * R + lane) * 2];
        float4 w1 = wp[(c * R + lane) * 2 + 1];
#pragma unroll
        for (int g = 0; g < G; ++g) {
            u[g][0] = fmaf(xv[g], w0.x, u[g][0]);
            u[g][1] = fmaf(xv[g], w0.y, u[g][1]);
            u[g][2] = fmaf(xv[g], w0.z, u[g][2]);
            u[g][3] = fmaf(xv[g], w0.w, u[g][3]);
            u[g][4] = fmaf(xv[g], w1.x, u[g][4]);
            u[g][5] = fmaf(xv[g], w1.y, u[g][5]);
            u[g][6] = fmaf(xv[g], w1.z, u[g][6]);
            u[g][7] = fmaf(xv[g], w1.w, u[g][7]);
        }
    }
#pragma unroll
    for (int g = 0; g < G; ++g) {
        float4* dst = (float4*)(uhat + (((size_t)(b0 + g) * 32 + n) * R + lane) * O);
        dst[0] = make_float4(u[g][0], u[g][1], u[g][2], u[g][3]);
        dst[1] = make_float4(u[g][4], u[g][5], u[g][6], u[g][7]);
    }
}

// K2: routing iterations. One block per b; thread = (n, rp).
__global__ __launch_bounds__(256)
void routing1_iter(const float* __restrict__ uhat, float* __restrict__ v1)
{
    constexpr int O = 8;
    const int t  = threadIdx.x;
    const int b  = blockIdx.x;
    const int n  = t >> 3;
    const int rp = t & 7;

    float u[8][O];
    {
        const float4* up = (const float4*)(uhat + (((size_t)b * 32 + n) * 64 + rp * 8) * O);
#pragma unroll
        for (int i = 0; i < 16; ++i) {
            float4 w = up[i];
            u[i >> 1][(i & 1) * 4 + 0] = w.x;
            u[i >> 1][(i & 1) * 4 + 1] = w.y;
            u[i >> 1][(i & 1) * 4 + 2] = w.z;
            u[i >> 1][(i & 1) * 4 + 3] = w.w;
        }
    }

    float bij[8];
#pragma unroll
    for (int k = 0; k < 8; ++k) bij[k] = 0.f;
    float s[O];

#pragma unroll
    for (int it = 0; it < 3; ++it) {
        float e[8];
        float inv;
        if (it == 0) {
#pragma unroll
            for (int k = 0; k < 8; ++k) e[k] = 1.f;
            inv = 1.0f / 64.0f;
        } else {
            float mx = bij[0];
#pragma unroll
            for (int k = 1; k < 8; ++k) mx = fmaxf(mx, bij[k]);
#pragma unroll
            for (int m = 1; m < 8; m <<= 1) mx = fmaxf(mx, __shfl_xor(mx, m, 64));
            float sum = 0.f;
#pragma unroll
            for (int k = 0; k < 8; ++k) { e[k] = __expf(bij[k] - mx); sum += e[k]; }
#pragma unroll
            for (int m = 1; m < 8; m <<= 1) sum += __shfl_xor(sum, m, 64);
            inv = 1.f / sum;
        }
        float ta[O];
#pragma unroll
        for (int o = 0; o < O; ++o) ta[o] = 0.f;
#pragma unroll
        for (int k = 0; k < 8; ++k)
#pragma unroll
            for (int o = 0; o < O; ++o) ta[o] = fmaf(e[k], u[k][o], ta[o]);
#pragma unroll
        for (int m = 1; m < 8; m <<= 1)
#pragma unroll
            for (int o = 0; o < O; ++o) ta[o] += __shfl_xor(ta[o], m, 64);
        float nr = 0.f;
#pragma unroll
        for (int o = 0; o < O; ++o) { s[o] = ta[o] * inv; nr = fmaf(s[o], s[o], nr); }
        float scale = nr / (1.f + nr) / sqrtf(nr + 1e-9f);
#pragma unroll
        for (int o = 0; o < O; ++o) s[o] *= scale;
        if (it < 2) {
#pragma unroll
            for (int k = 0; k < 8; ++k) {
                float d = 0.f;
#pragma unroll
                for (int o = 0; o < O; ++o) d = fmaf(u[k][o], s[o], d);
                bij[k] += d;
            }
        }
    }
    float outv = s[0];
#pragma unroll
    for (int o = 1; o < O; ++o) outv = (rp == o) ? s[o] : outv;
    v1[(size_t)b * 256 + n * 8 + rp] = outv;
}

// Routing stage 2 + FC, register-resident. One block per b, 4 waves.
__global__ __launch_bounds__(256)
void routing2_fc(const float* __restrict__ v1, const float* __restrict__ W,
                 const float* __restrict__ fcw, const float* __restrict__ fcb,
                 float* __restrict__ out)
{
    constexpr int R = 32, C = 8, O = 16;
    __shared__ float vv[240];

    const int t  = threadIdx.x;
    const int b  = blockIdx.x;
    const int wv = t >> 6;
    const int lane = t & 63;
    const int nh = lane >> 5;
    const int r  = lane & 31;

    const float4* xr = (const float4*)(v1 + (size_t)b * 256 + r * 8);
    float4 x0 = xr[0], x1 = xr[1];
    float xv[8] = {x0.x, x0.y, x0.z, x0.w, x1.x, x1.y, x1.z, x1.w};

    float u[2][O];
    int nn[2];
#pragma unroll
    for (int p = 0; p < 2; ++p) {
        int n = wv * 4 + p * 2 + nh;
        nn[p] = n;
        int ncl = n < 15 ? n : 14;
        const float4* wp = (const float4*)(W + ((size_t)(ncl * R + r) * C) * O);
#pragma unroll
        for (int o = 0; o < O; ++o) u[p][o] = 0.f;
#pragma unroll
        for (int c = 0; c < C; ++c) {
#pragma unroll
            for (int j = 0; j < 4; ++j) {
                float4 w4 = wp[c * 4 + j];
                u[p][j * 4 + 0] = fmaf(xv[c], w4.x, u[p][j * 4 + 0]);
                u[p][j * 4 + 1] = fmaf(xv[c], w4.y, u[p][j * 4 + 1]);
                u[p][j * 4 + 2] = fmaf(xv[c], w4.z, u[p][j * 4 + 2]);
                u[p][j * 4 + 3] = fmaf(xv[c], w4.w, u[p][j * 4 + 3]);
            }
        }
    }

    float bij[2] = {0.f, 0.f};
    float s[2][O];
#pragma unroll
    for (int it = 0; it < 3; ++it) {
#pragma unroll
        for (int p = 0; p < 2; ++p) {
            float cc;
            if (it == 0) {
                cc = 1.0f / 32.0f;
            } else {
                float mx = bij[p];
#pragma unroll
                for (int w = 1; w < 32; w <<= 1) mx = fmaxf(mx, __shfl_xor(mx, w, 32));
                float e = __expf(bij[p] - mx);
                float sum = e;
#pragma unroll
                for (int w = 1; w < 32; w <<= 1) sum += __shfl_xor(sum, w, 32);
                cc = e / sum;
            }
#pragma unroll
            for (int o = 0; o < O; ++o) s[p][o] = cc * u[p][o];
        }
#pragma unroll
        for (int w = 1; w < 32; w <<= 1)
#pragma unroll
            for (int p = 0; p < 2; ++p)
#pragma unroll
                for (int o = 0; o < O; ++o) s[p][o] += __shfl_xor(s[p][o], w, 32);
#pragma unroll
        for (int p = 0; p < 2; ++p) {
            float nr = 0.f;
#pragma unroll
            for (int o = 0; o < O; ++o) nr = fmaf(s[p][o], s[p][o], nr);
            float scale = nr / (1.f + nr) / sqrtf(nr + 1e-9f);
#pragma unroll
            for (int o = 0; o < O; ++o) s[p][o] *= scale;
            if (it < 2) {
                float d = 0.f;
#pragma unroll
                for (int o = 0; o < O; ++o) d = fmaf(u[p][o], s[p][o], d);
                bij[p] += d;
            }
        }
    }
#pragma unroll
    for (int p = 0; p < 2; ++p) {
        float outv = 0.f;
#pragma unroll
        for (int o = 0; o < O; ++o) outv = (r == o) ? s[p][o] : outv;
        if (r < O && nn[p] < 15) vv[nn[p] * O + r] = outv;
    }
    __syncthreads();
    if (t < 240) {
        int j = t >> 4, k0 = t & 15;
        float acc = 0.f;
        for (int k = k0; k < 240; k += 16) acc = fmaf(vv[k], fcw[j * 240 + k], acc);
#pragma unroll
        for (int w = 1; w < 16; w <<= 1) acc += __shfl_xor(acc, w, 16);
        if (k0 == 0) out[(size_t)b * 15 + j] = acc + fcb[j];
    }
}

extern "C" void kernel_launch(void* const* d_in, const int* in_sizes, int n_in,
                              void* d_out, int out_size, void* d_ws, size_t ws_size,
                              hipStream_t stream) {
    const float* x    = (const float*)d_in[0];
    const float* w1   = (const float*)d_in[1];
    const float* b1   = (const float*)d_in[2];
    const float* w2   = (const float*)d_in[3];
    const float* b2   = (const float*)d_in[4];
    const float* w3   = (const float*)d_in[5];
    const float* b3   = (const float*)d_in[6];
    const float* rw1  = (const float*)d_in[7];
    const float* rw2  = (const float*)d_in[8];
    const float* fcw  = (const float*)d_in[9];
    const float* fcb  = (const float*)d_in[10];
    float* out = (float*)d_out;

    const int B = 512;
    float* ws = (float*)d_ws;
    float* uhat = ws;                                // [512,32,64,8] = 8,388,608
    float* h3   = uhat + (size_t)8388608;            // [512,32,8,8]  = 1,048,576
    float* v1   = h3 + (size_t)B * 32 * 8 * 8;       // [512,32,8]    =   131,072
    float* Wt   = v1 + (size_t)B * 256;              // [32,32,64,8]  =   524,288

    conv_stack<<<B, 256, 0, stream>>>(x, w1, b1, w2, b2, w3, b3, h3);
    transpose_w1<<<(32 * 32 * 64 * 2 + 255) / 256, 256, 0, stream>>>(rw1, Wt);
    {
        dim3 grid(B / 8, 8);   // K1: 512 blocks
        routing1_einsum<<<grid, 256, 0, stream>>>(h3, Wt, uhat);
    }
    routing1_iter<<<B, 256, 0, stream>>>(uhat, v1);
    routing2_fc<<<B, 256, 0, stream>>>(v1, rw2, fcw, fcb, out);
}